// Round 12
// baseline (542.495 us; speedup 1.0000x reference)
//
#include <hip/hip_runtime.h>
#include <stdint.h>

#define NS 100000
#define NR 200000
#define EE 1000000
#define DD 128
#define NB 50
#define NSP 2000
#define NRP 4000
#define BSH 10
#define NBR 196   /* ceil(NR/1024) */
#define NBS 98    /* ceil(NS/1024) */
#define CHUNK 8192

typedef short bf16x8 __attribute__((ext_vector_type(8)));
typedef float f32x4 __attribute__((ext_vector_type(4)));
typedef float f32x2 __attribute__((ext_vector_type(2)));
typedef unsigned u32x4 __attribute__((ext_vector_type(4)));
typedef unsigned u32x2 __attribute__((ext_vector_type(2)));

__device__ __forceinline__ unsigned short f2bf(float f){
  unsigned u = __float_as_uint(f);
  u = (u + 0x7FFFu + ((u >> 16) & 1u)) >> 16;
  return (unsigned short)u;
}
__device__ __forceinline__ float bf2f(unsigned short s){
  return __uint_as_float(((unsigned)s) << 16);
}
__device__ __forceinline__ unsigned packbf(float a, float b){
  return (unsigned)f2bf(a) | ((unsigned)f2bf(b) << 16);
}
__device__ __forceinline__ float bflo(unsigned p){ return __uint_as_float(p << 16); }
__device__ __forceinline__ float bfhi(unsigned p){ return __uint_as_float(p & 0xFFFF0000u); }

// fp8 e4m3 helpers (HW cvt; self-consistent encode/decode)
__device__ __forceinline__ u32x2 packf8(const float* v){
  u32x2 r;
  unsigned w = __builtin_amdgcn_cvt_pk_fp8_f32(v[0], v[1], 0u, false);
  r.x = __builtin_amdgcn_cvt_pk_fp8_f32(v[2], v[3], w, true);
  w = __builtin_amdgcn_cvt_pk_fp8_f32(v[4], v[5], 0u, false);
  r.y = __builtin_amdgcn_cvt_pk_fp8_f32(v[6], v[7], w, true);
  return r;
}

// ---------------- weight pre-pack into MFMA fragment order ----------------
// Wp[mat][ct][ks][lane][j] = W[mat][k = ks*32 + (lane>>4)*8 + j][col = ct*16 + (lane&15)]
__global__ void pack_w(const float* __restrict__ Wr, const float* __restrict__ Ws,
                       unsigned short* __restrict__ Wp){
  int g = blockIdx.x*256 + threadIdx.x;   // 4*32768 = 131072 total
  if (g >= 4*32768) return;
  int j = g & 7; int rest = g >> 3;
  int lane = rest & 63; rest >>= 6;
  int ks = rest & 7; rest >>= 3;
  int ct = rest & 7; int mat = rest >> 3;
  int k  = ks*32 + (lane >> 4)*8 + j;
  int cc = ct*16 + (lane & 15);
  const float* src = (mat < 2) ? (Wr + (size_t)mat*256*DD) : (Ws + (size_t)(mat-2)*256*DD);
  Wp[g] = f2bf(src[(size_t)k*DD + cc]);
}

// ---------------- fused embedding init: bf16 + fp8 shadow ----------------
__global__ __launch_bounds__(256) void init_all(const int* __restrict__ si, const int* __restrict__ ext,
        const int* __restrict__ tid, const float* __restrict__ pp,
        const float* __restrict__ st, const float* __restrict__ et, const float* __restrict__ tt,
        const float* __restrict__ Wpar, const float* __restrict__ bpar,
        unsigned short* __restrict__ hs, unsigned short* __restrict__ hr,
        unsigned char* __restrict__ f8S, unsigned char* __restrict__ f8R){
  int g = blockIdx.x*256 + threadIdx.x;   // (NS+NR)*16 total
  int row = g >> 4, colb = (g & 15) * 8;
  float v[8];
  if (row < NS){
    const float* a = st + (size_t)si[row]*DD + colb;
    const float* b = et + (size_t)ext[row]*DD + colb;
    float4 x0 = ((const float4*)a)[0], x1 = ((const float4*)a)[1];
    float4 y0 = ((const float4*)b)[0], y1 = ((const float4*)b)[1];
    v[0]=x0.x+y0.x; v[1]=x0.y+y0.y; v[2]=x0.z+y0.z; v[3]=x0.w+y0.w;
    v[4]=x1.x+y1.x; v[5]=x1.y+y1.y; v[6]=x1.z+y1.z; v[7]=x1.w+y1.w;
    u32x4 o;
    o.x = packbf(v[0],v[1]); o.y = packbf(v[2],v[3]);
    o.z = packbf(v[4],v[5]); o.w = packbf(v[6],v[7]);
    *(u32x4*)(hs + (size_t)row*DD + colb) = o;
    *(u32x2*)(f8S + (size_t)row*DD + colb) = packf8(v);
  } else {
    int r = row - NS;
    const float* tb = tt + (size_t)tid[r]*DD + colb;
    float4 a0 = ((const float4*)tb)[0], a1 = ((const float4*)tb)[1];
    float4 b0 = ((const float4*)(bpar+colb))[0], b1 = ((const float4*)(bpar+colb))[1];
    a0.x += b0.x; a0.y += b0.y; a0.z += b0.z; a0.w += b0.w;
    a1.x += b1.x; a1.y += b1.y; a1.z += b1.z; a1.w += b1.w;
    const float* pr = pp + (size_t)r*8;
    float4 p0 = ((const float4*)pr)[0], p1 = ((const float4*)pr)[1];
    float w[8] = {p0.x,p0.y,p0.z,p0.w,p1.x,p1.y,p1.z,p1.w};
    #pragma unroll
    for (int p = 0; p < 8; p++){
      float4 w0 = ((const float4*)(Wpar + p*DD + colb))[0];
      float4 w1 = ((const float4*)(Wpar + p*DD + colb))[1];
      a0.x += w[p]*w0.x; a0.y += w[p]*w0.y; a0.z += w[p]*w0.z; a0.w += w[p]*w0.w;
      a1.x += w[p]*w1.x; a1.y += w[p]*w1.y; a1.z += w[p]*w1.z; a1.w += w[p]*w1.w;
    }
    v[0]=a0.x; v[1]=a0.y; v[2]=a0.z; v[3]=a0.w;
    v[4]=a1.x; v[5]=a1.y; v[6]=a1.z; v[7]=a1.w;
    u32x4 o;
    o.x = packbf(v[0],v[1]); o.y = packbf(v[2],v[3]);
    o.z = packbf(v[4],v[5]); o.w = packbf(v[6],v[7]);
    *(u32x4*)(hr + (size_t)r*DD + colb) = o;
    *(u32x2*)(f8R + (size_t)r*DD + colb) = packf8(v);
  }
}

// ---------------- bucketed CSR build ----------------
__global__ __launch_bounds__(256) void bucket_hist(const int* __restrict__ er, const int* __restrict__ es,
                                                   int* __restrict__ gcnt){
  __shared__ int cnt[NBR + NBS];
  int t = threadIdx.x;
  for (int j = t; j < NBR + NBS; j += 256) cnt[j] = 0;
  __syncthreads();
  long i0 = (long)blockIdx.x * 2048;
  for (int j = t; j < 2048; j += 256){
    long i = i0 + j;
    if (i < EE){
      atomicAdd(&cnt[er[i] >> BSH], 1);
      atomicAdd(&cnt[NBR + (es[i] >> BSH)], 1);
    }
  }
  __syncthreads();
  for (int j = t; j < NBR + NBS; j += 256)
    if (cnt[j]) atomicAdd(&gcnt[j], cnt[j]);
}

__global__ __launch_bounds__(256) void bucket_scan(const int* __restrict__ gcnt,
        int* __restrict__ bktOffR, int* __restrict__ bktOffS,
        int* __restrict__ gCurR, int* __restrict__ gCurS){
  __shared__ int a[256];
  int t = threadIdx.x;
  int own = (t < NBR) ? gcnt[t] : 0;
  a[t] = own; __syncthreads();
  for (int d = 1; d < 256; d <<= 1){
    int x = (t >= d) ? a[t-d] : 0;
    __syncthreads(); a[t] += x; __syncthreads();
  }
  if (t < NBR){ int v = a[t] - own; bktOffR[t] = v; gCurR[t] = v; }
  if (t == 0) bktOffR[NBR] = EE;
  __syncthreads();
  own = (t < NBS) ? gcnt[NBR + t] : 0;
  a[t] = own; __syncthreads();
  for (int d = 1; d < 256; d <<= 1){
    int x = (t >= d) ? a[t-d] : 0;
    __syncthreads(); a[t] += x; __syncthreads();
  }
  if (t < NBS){ int v = a[t] - own; bktOffS[t] = v; gCurS[t] = v; }
  if (t == 0) bktOffS[NBS] = EE;
}

__global__ __launch_bounds__(256) void bin_edges(const int* __restrict__ er, const int* __restrict__ es,
        int* __restrict__ gCurR, int* __restrict__ gCurS,
        unsigned* __restrict__ recR, unsigned* __restrict__ recS){
  __shared__ unsigned stage[CHUNK];
  __shared__ unsigned char stageb[CHUNK];
  __shared__ int cnt[256], scn[256], pref[256], gbase[256], lcur[256];
  int t = threadIdx.x;
  int side = blockIdx.y;
  const int* dest = side ? es : er;
  const int* srca = side ? er : es;
  int* gCur = side ? gCurS : gCurR;
  unsigned* rec = side ? recS : recR;
  int nbkt = side ? NBS : NBR;
  long i0 = (long)blockIdx.x * CHUNK;
  int n = (EE - i0 < CHUNK) ? (int)(EE - i0) : CHUNK;
  cnt[t] = 0;
  __syncthreads();
  for (int j = t; j < n; j += 256)
    atomicAdd(&cnt[dest[i0 + j] >> BSH], 1);
  __syncthreads();
  scn[t] = cnt[t];
  __syncthreads();
  for (int d = 1; d < 256; d <<= 1){
    int x = (t >= d) ? scn[t-d] : 0;
    __syncthreads(); scn[t] += x; __syncthreads();
  }
  pref[t] = scn[t] - cnt[t];
  lcur[t] = scn[t] - cnt[t];
  if (t < nbkt && cnt[t] > 0) gbase[t] = atomicAdd(&gCur[t], cnt[t]);
  __syncthreads();
  for (int j = t; j < n; j += 256){
    int d = dest[i0 + j];
    int s = srca[i0 + j];
    int b = d >> BSH;
    int p = atomicAdd(&lcur[b], 1);
    stage[p] = ((unsigned)(d - (b << BSH)) << 18) | (unsigned)s;
    stageb[p] = (unsigned char)b;
  }
  __syncthreads();
  for (int e = t; e < n; e += 256){
    int b = stageb[e];
    rec[gbase[b] + (e - pref[b])] = stage[e];
  }
}

// Stage 4: scatter FULL records (dloc<<18 | src) — consumers use dest-local row bits.
__global__ __launch_bounds__(256) void build_csr(const unsigned* __restrict__ recR, const unsigned* __restrict__ recS,
        const int* __restrict__ bktOffR, const int* __restrict__ bktOffS,
        unsigned* __restrict__ csrR, unsigned* __restrict__ csrS,
        int* __restrict__ offsR, int* __restrict__ offsS){
  __shared__ int hist[1024], pref[1024], cur[1024], ws[256];
  int t = threadIdx.x;
  int bb = blockIdx.x;
  const unsigned* rec; const int* bktOff; unsigned* csr; int* offs; int N;
  if (bb < NBR){ rec = recR; bktOff = bktOffR; csr = csrR; offs = offsR; N = NR; }
  else { bb -= NBR; rec = recS; bktOff = bktOffS; csr = csrS; offs = offsS; N = NS; }
  int d0 = bb << BSH;
  int base = bktOff[bb], cnt_ = bktOff[bb+1] - base;
  #pragma unroll
  for (int j = 0; j < 4; j++) hist[t*4+j] = 0;
  __syncthreads();
  for (int e = t; e < cnt_; e += 256)
    atomicAdd(&hist[rec[base + e] >> 18], 1);
  __syncthreads();
  int s = 0, h[4];
  #pragma unroll
  for (int j = 0; j < 4; j++){ h[j] = hist[t*4+j]; s += h[j]; }
  ws[t] = s;
  __syncthreads();
  for (int d = 1; d < 256; d <<= 1){
    int x = (t >= d) ? ws[t-d] : 0;
    __syncthreads(); ws[t] += x; __syncthreads();
  }
  int run = ws[t] - s;
  #pragma unroll
  for (int j = 0; j < 4; j++){ pref[t*4+j] = run; cur[t*4+j] = base + run; run += h[j]; }
  __syncthreads();
  int DPB = N - d0; if (DPB > 1024) DPB = 1024;
  #pragma unroll
  for (int j = 0; j < 4; j++){
    int i = t*4 + j;
    if (i < DPB) offs[d0 + i] = base + pref[i];
  }
  if (t == 0 && d0 + DPB == N) offs[N] = EE;
  __syncthreads();
  for (int e = t; e < cnt_; e += 256){
    unsigned r = rec[base + e];
    int pos = atomicAdd(&cur[r >> 18], 1);
    csr[pos] = r;                        // keep dloc bits
  }
}

// ============ fused streaming-gather(fp8) + concat-GEMM + bias + relu ============
// Block = one 32-row tile. Phase 1: each wave owns 8 rows; one edge per
// wave-instruction (64 lanes x 2B fp8 = a full 128B row), 4-deep prefetch ring,
// plain swizzled LDS store at row boundaries (rows wave-exclusive).
// Phase 2: swapped-operand MFMA (W as A, H/msg as B) -> bf16 + fp8 shadow stores.
__global__ __launch_bounds__(256) void fused_layer(
        const unsigned char* __restrict__ g8,      // fp8 gather source rows
        const unsigned short* __restrict__ hself,  // self features (bf16)
        const int* __restrict__ offs, const unsigned* __restrict__ csr,
        const unsigned short* __restrict__ Wp, const float* __restrict__ bias,
        unsigned short* __restrict__ hout, unsigned char* __restrict__ hout8)
{
  __shared__ unsigned short msgT[32*DD];   // 8 KB; 16B chunks swizzled: slot = c16 ^ (row&7)
  int t = threadIdx.x;
  int lane = t & 63;
  int w = t >> 6;
  int quad = lane >> 4, rlo = lane & 15;
  int row0 = blockIdx.x * 32;

  // zero-init msg tile (covers empty rows)
  for (int i = t; i < 2048; i += 256) ((unsigned*)msgT)[i] = 0u;
  __syncthreads();

  // ---- phase 1: wave streams the edges of its 8 rows (fp8, 2B/lane) ----
  {
    int rbeg = row0 + w*8;
    int k  = offs[rbeg];
    int ke = offs[rbeg + 8];
    int c16 = lane >> 2, sub4 = lane & 3;
    float a0 = 0.f, a1 = 0.f;
    int cur = -1;
    unsigned rc[4]; unsigned short pv[4];
    if (k < ke){
      #pragma unroll
      for (int i = 0; i < 4; i++){
        int kk = (k + i < ke) ? (k + i) : (ke - 1);
        rc[i] = csr[kk];
      }
      #pragma unroll
      for (int i = 0; i < 4; i++)
        pv[i] = *(const unsigned short*)(g8 + (size_t)(rc[i] & 0x3FFFF)*DD + lane*2);
      while (k < ke){
        unsigned rc2[4]; unsigned short pv2[4];
        int kn = k + 4;
        #pragma unroll
        for (int i = 0; i < 4; i++){
          int kk = (kn + i < ke) ? (kn + i) : (ke - 1);
          rc2[i] = csr[kk];
        }
        #pragma unroll
        for (int i = 0; i < 4; i++)
          pv2[i] = *(const unsigned short*)(g8 + (size_t)(rc2[i] & 0x3FFFF)*DD + lane*2);
        #pragma unroll
        for (int i = 0; i < 4; i++){
          if (k + i < ke){
            int dl = (int)((rc[i] >> 18) & 31);     // wave-uniform tile-local row
            if (dl != cur){
              if (cur >= 0)
                *(unsigned*)(msgT + cur*DD + ((c16 ^ (cur & 7)) << 3) + (sub4 << 1)) = packbf(a0, a1);
              a0 = 0.f; a1 = 0.f;
              cur = dl;
            }
            f32x2 f = __builtin_amdgcn_cvt_pk_f32_fp8((unsigned)pv[i], false);
            a0 += f.x; a1 += f.y;
          }
        }
        #pragma unroll
        for (int i = 0; i < 4; i++){ rc[i] = rc2[i]; pv[i] = pv2[i]; }
        k = kn;
      }
      if (cur >= 0)
        *(unsigned*)(msgT + cur*DD + ((c16 ^ (cur & 7)) << 3) + (sub4 << 1)) = packbf(a0, a1);
    }
  }
  __syncthreads();

  // ---- phase 2: MFMA. W = A-operand, H/msg = B-operand. Wave -> 32-col strip. ----
  int ct0 = w * 2;
  bf16x8 wf[16];                         // [ks][c]
  #pragma unroll
  for (int ks = 0; ks < 8; ks++){
    wf[ks*2+0] = *(const bf16x8*)(Wp + (size_t)(((ct0+0)*8 + ks)*64 + lane) * 8);
    wf[ks*2+1] = *(const bf16x8*)(Wp + (size_t)(((ct0+1)*8 + ks)*64 + lane) * 8);
  }
  bf16x8 Hb0[4], Hb1[4];
  #pragma unroll
  for (int ks = 0; ks < 4; ks++){
    int kloc = ks*32 + quad*8;
    Hb0[ks] = *(const bf16x8*)(hself + (size_t)(row0 + rlo) * DD + kloc);
    Hb1[ks] = *(const bf16x8*)(hself + (size_t)(row0 + 16 + rlo) * DD + kloc);
  }
  bf16x8 Mb0[4], Mb1[4];
  #pragma unroll
  for (int ks2 = 0; ks2 < 4; ks2++){
    int c8 = ks2*4 + quad;               // 16B chunk index 0..15
    int lr0 = rlo, lr1 = 16 + rlo;
    Mb0[ks2] = *(const bf16x8*)(msgT + lr0*DD + ((c8 ^ (lr0 & 7)) * 8));
    Mb1[ks2] = *(const bf16x8*)(msgT + lr1*DD + ((c8 ^ (lr1 & 7)) * 8));
  }

  f32x4 acc[2][2];
  #pragma unroll
  for (int i = 0; i < 2; i++)
    #pragma unroll
    for (int j = 0; j < 2; j++){ f32x4 z = {0.f,0.f,0.f,0.f}; acc[i][j] = z; }

  #pragma unroll
  for (int ks = 0; ks < 4; ks++){
    acc[0][0] = __builtin_amdgcn_mfma_f32_16x16x32_bf16(wf[ks*2+0], Hb0[ks], acc[0][0], 0, 0, 0);
    acc[0][1] = __builtin_amdgcn_mfma_f32_16x16x32_bf16(wf[ks*2+1], Hb0[ks], acc[0][1], 0, 0, 0);
    acc[1][0] = __builtin_amdgcn_mfma_f32_16x16x32_bf16(wf[ks*2+0], Hb1[ks], acc[1][0], 0, 0, 0);
    acc[1][1] = __builtin_amdgcn_mfma_f32_16x16x32_bf16(wf[ks*2+1], Hb1[ks], acc[1][1], 0, 0, 0);
  }
  #pragma unroll
  for (int ks2 = 0; ks2 < 4; ks2++){
    int ks = 4 + ks2;
    acc[0][0] = __builtin_amdgcn_mfma_f32_16x16x32_bf16(wf[ks*2+0], Mb0[ks2], acc[0][0], 0, 0, 0);
    acc[0][1] = __builtin_amdgcn_mfma_f32_16x16x32_bf16(wf[ks*2+1], Mb0[ks2], acc[0][1], 0, 0, 0);
    acc[1][0] = __builtin_amdgcn_mfma_f32_16x16x32_bf16(wf[ks*2+0], Mb1[ks2], acc[1][0], 0, 0, 0);
    acc[1][1] = __builtin_amdgcn_mfma_f32_16x16x32_bf16(wf[ks*2+1], Mb1[ks2], acc[1][1], 0, 0, 0);
  }

  // epilogue: acc[rb][c][i] = out[row0+rb*16+rlo][(ct0+c)*16 + quad*4 + i]
  #pragma unroll
  for (int c = 0; c < 2; c++){
    float4 bv = *(const float4*)(bias + (ct0+c)*16 + quad*4);
    #pragma unroll
    for (int rb = 0; rb < 2; rb++){
      int row = row0 + rb*16 + rlo;
      float v0 = acc[rb][c][0] + bv.x;
      float v1 = acc[rb][c][1] + bv.y;
      float v2 = acc[rb][c][2] + bv.z;
      float v3 = acc[rb][c][3] + bv.w;
      v0 = v0 > 0.f ? v0 : 0.f;
      v1 = v1 > 0.f ? v1 : 0.f;
      v2 = v2 > 0.f ? v2 : 0.f;
      v3 = v3 > 0.f ? v3 : 0.f;
      u32x2 o; o.x = packbf(v0, v1); o.y = packbf(v2, v3);
      *(u32x2*)(hout + (size_t)row*DD + (ct0+c)*16 + quad*4) = o;
      unsigned w8 = __builtin_amdgcn_cvt_pk_fp8_f32(v0, v1, 0u, false);
      w8 = __builtin_amdgcn_cvt_pk_fp8_f32(v2, v3, w8, true);
      *(unsigned*)(hout8 + (size_t)row*DD + (ct0+c)*16 + quad*4) = w8;
    }
  }
}

// ---------------- segment-mean pooling: 16B loads, 2-stage reduce ----------------
__global__ __launch_bounds__(256) void pool(const unsigned short* __restrict__ hs,
        const unsigned short* __restrict__ hr, float* __restrict__ out){
  __shared__ float red[16][128];
  int b = blockIdx.x, part = blockIdx.y;   // part<4: species, else reactions (500 rows each)
  int t = threadIdx.x;
  int rg = t >> 4, sub = t & 15;
  const unsigned short* src; int row0, outoff; float scale;
  if (part < 4){ src = hs; row0 = b*NSP + part*500; outoff = b*256; scale = 1.f/NSP; }
  else { src = hr; row0 = b*NRP + (part-4)*500; outoff = b*256 + 128; scale = 1.f/NRP; }
  float a0=0,a1=0,a2=0,a3=0,a4=0,a5=0,a6=0,a7=0;
  for (int r = rg; r < 500; r += 16){
    u32x4 p = *(const u32x4*)(src + (size_t)(row0+r)*DD + sub*8);
    a0 += bflo(p.x); a1 += bfhi(p.x);
    a2 += bflo(p.y); a3 += bfhi(p.y);
    a4 += bflo(p.z); a5 += bfhi(p.z);
    a6 += bflo(p.w); a7 += bfhi(p.w);
  }
  float* rr = &red[rg][sub*8];
  rr[0]=a0; rr[1]=a1; rr[2]=a2; rr[3]=a3; rr[4]=a4; rr[5]=a5; rr[6]=a6; rr[7]=a7;
  __syncthreads();
  if (t < 128){
    float s = 0.f;
    #pragma unroll
    for (int g = 0; g < 16; g++) s += red[g][t];
    atomicAdd(&out[outoff + t], s * scale);
  }
}

extern "C" void kernel_launch(void* const* d_in, const int* in_sizes, int n_in,
                              void* d_out, int out_size, void* d_ws, size_t ws_size,
                              hipStream_t stream)
{
  const int*   si   = (const int*)d_in[0];
  const int*   ext  = (const int*)d_in[1];
  const int*   tid  = (const int*)d_in[2];
  const float* pp   = (const float*)d_in[3];
  const int*   es   = (const int*)d_in[4];
  const int*   er   = (const int*)d_in[5];
  const float* st   = (const float*)d_in[8];
  const float* et   = (const float*)d_in[9];
  const float* tt   = (const float*)d_in[10];
  const float* Wpar = (const float*)d_in[11];
  const float* bpar = (const float*)d_in[12];
  const float* Wr   = (const float*)d_in[13];
  const float* br   = (const float*)d_in[14];
  const float* Ws   = (const float*)d_in[15];
  const float* bs   = (const float*)d_in[16];
  float* out = (float*)d_out;

  char* basep = (char*)d_ws; size_t off = 0;
  auto alloc = [&](size_t bytes)->char*{
    char* r = basep + off; off = (off + bytes + 255) & ~(size_t)255; return r;
  };
  unsigned short* hs0 = (unsigned short*)alloc((size_t)NS*DD*2);
  unsigned short* hs1 = (unsigned short*)alloc((size_t)NS*DD*2);
  unsigned short* hr0 = (unsigned short*)alloc((size_t)NR*DD*2);
  unsigned short* hr1 = (unsigned short*)alloc((size_t)NR*DD*2);
  unsigned char*  f8S = (unsigned char*)alloc((size_t)NS*DD);   // fp8 shadow (species side)
  unsigned char*  f8R = (unsigned char*)alloc((size_t)NR*DD);   // fp8 shadow (reaction side)
  unsigned short* Wp  = (unsigned short*)alloc((size_t)4*32768*2);
  int* offsR = (int*)alloc((size_t)(NR+1)*4);
  int* offsS = (int*)alloc((size_t)(NS+1)*4);
  unsigned* csrR = (unsigned*)alloc((size_t)EE*4);
  unsigned* csrS = (unsigned*)alloc((size_t)EE*4);
  int* gcnt   = (int*)alloc(2048);
  int* bktOffR= (int*)alloc(2048);
  int* bktOffS= (int*)alloc(2048);
  int* gCurR  = (int*)alloc(2048);
  int* gCurS  = (int*)alloc(2048);
  // rec arrays only live during CSR build; alias into the ping buffers
  // (hs1 / hr1 are first written at layer-0 fused dispatches, after build_csr).
  unsigned* recR = (unsigned*)hs1;            // 4 MB within 25.6 MB
  unsigned* recS = (unsigned*)hr1;            // 4 MB within 51.2 MB

  hipMemsetAsync(gcnt, 0, 2048, stream);
  hipMemsetAsync(d_out, 0, (size_t)out_size*4, stream);

  pack_w<<<512, 256, 0, stream>>>(Wr, Ws, Wp);
  init_all<<<(NS+NR)*16/256, 256, 0, stream>>>(si, ext, tid, pp, st, et, tt, Wpar, bpar,
                                               hs0, hr0, f8S, f8R);

  bucket_hist<<<(EE + 2047)/2048, 256, 0, stream>>>(er, es, gcnt);
  bucket_scan<<<1, 256, 0, stream>>>(gcnt, bktOffR, bktOffS, gCurR, gCurS);
  bin_edges<<<dim3((EE + CHUNK - 1)/CHUNK, 2), 256, 0, stream>>>(er, es, gCurR, gCurS, recR, recS);
  build_csr<<<NBR + NBS, 256, 0, stream>>>(recR, recS, bktOffR, bktOffS, csrR, csrS, offsR, offsS);

  // layer 0: R gathers f8S, writes hr1 + f8R; S gathers f8R, writes hs1 + f8S
  fused_layer<<<NR/32, 256, 0, stream>>>(f8S, hr0, offsR, csrR, Wp + (size_t)0*32768, br + (size_t)0*DD, hr1, f8R);
  fused_layer<<<NS/32, 256, 0, stream>>>(f8R, hs0, offsS, csrS, Wp + (size_t)2*32768, bs + (size_t)0*DD, hs1, f8S);
  // layer 1
  fused_layer<<<NR/32, 256, 0, stream>>>(f8S, hr1, offsR, csrR, Wp + (size_t)1*32768, br + (size_t)1*DD, hr0, f8R);
  fused_layer<<<NS/32, 256, 0, stream>>>(f8R, hs1, offsS, csrS, Wp + (size_t)3*32768, bs + (size_t)1*DD, hs0, f8S);

  pool<<<dim3(NB, 12), 256, 0, stream>>>(hs0, hr0, out);
}

// Round 13
// 459.811 us; speedup vs baseline: 1.1798x; 1.1798x over previous
//
#include <hip/hip_runtime.h>
#include <stdint.h>

#define NS 100000
#define NR 200000
#define EE 1000000
#define DD 128
#define NB 50
#define NSP 2000
#define NRP 4000
#define BSH 10
#define NBR 196   /* ceil(NR/1024) */
#define NBS 98    /* ceil(NS/1024) */
#define CHUNK 8192

typedef short bf16x8 __attribute__((ext_vector_type(8)));
typedef float f32x4 __attribute__((ext_vector_type(4)));
typedef unsigned u32x4 __attribute__((ext_vector_type(4)));
typedef unsigned u32x2 __attribute__((ext_vector_type(2)));

__device__ __forceinline__ unsigned short f2bf(float f){
  unsigned u = __float_as_uint(f);
  u = (u + 0x7FFFu + ((u >> 16) & 1u)) >> 16;
  return (unsigned short)u;
}
__device__ __forceinline__ float bf2f(unsigned short s){
  return __uint_as_float(((unsigned)s) << 16);
}
__device__ __forceinline__ unsigned packbf(float a, float b){
  return (unsigned)f2bf(a) | ((unsigned)f2bf(b) << 16);
}
__device__ __forceinline__ float bflo(unsigned p){ return __uint_as_float(p << 16); }
__device__ __forceinline__ float bfhi(unsigned p){ return __uint_as_float(p & 0xFFFF0000u); }

// ---------------- weight pre-pack into MFMA fragment order ----------------
// Wp[mat][ct][ks][lane][j] = W[mat][k = ks*32 + (lane>>4)*8 + j][col = ct*16 + (lane&15)]
__global__ void pack_w(const float* __restrict__ Wr, const float* __restrict__ Ws,
                       unsigned short* __restrict__ Wp){
  int g = blockIdx.x*256 + threadIdx.x;   // 4*32768 = 131072 total
  if (g >= 4*32768) return;
  int j = g & 7; int rest = g >> 3;
  int lane = rest & 63; rest >>= 6;
  int ks = rest & 7; rest >>= 3;
  int ct = rest & 7; int mat = rest >> 3;
  int k  = ks*32 + (lane >> 4)*8 + j;
  int cc = ct*16 + (lane & 15);
  const float* src = (mat < 2) ? (Wr + (size_t)mat*256*DD) : (Ws + (size_t)(mat-2)*256*DD);
  Wp[g] = f2bf(src[(size_t)k*DD + cc]);
}

// ---------------- fused embedding init: 16B stores, float4 reads ----------------
__global__ __launch_bounds__(256) void init_all(const int* __restrict__ si, const int* __restrict__ ext,
        const int* __restrict__ tid, const float* __restrict__ pp,
        const float* __restrict__ st, const float* __restrict__ et, const float* __restrict__ tt,
        const float* __restrict__ Wpar, const float* __restrict__ bpar,
        unsigned short* __restrict__ hs, unsigned short* __restrict__ hr){
  int g = blockIdx.x*256 + threadIdx.x;   // (NS+NR)*16 total
  int row = g >> 4, colb = (g & 15) * 8;
  if (row < NS){
    const float* a = st + (size_t)si[row]*DD + colb;
    const float* b = et + (size_t)ext[row]*DD + colb;
    float4 x0 = ((const float4*)a)[0], x1 = ((const float4*)a)[1];
    float4 y0 = ((const float4*)b)[0], y1 = ((const float4*)b)[1];
    u32x4 o;
    o.x = packbf(x0.x+y0.x, x0.y+y0.y);
    o.y = packbf(x0.z+y0.z, x0.w+y0.w);
    o.z = packbf(x1.x+y1.x, x1.y+y1.y);
    o.w = packbf(x1.z+y1.z, x1.w+y1.w);
    *(u32x4*)(hs + (size_t)row*DD + colb) = o;
  } else {
    int r = row - NS;
    const float* tb = tt + (size_t)tid[r]*DD + colb;
    float4 a0 = ((const float4*)tb)[0], a1 = ((const float4*)tb)[1];
    float4 b0 = ((const float4*)(bpar+colb))[0], b1 = ((const float4*)(bpar+colb))[1];
    a0.x += b0.x; a0.y += b0.y; a0.z += b0.z; a0.w += b0.w;
    a1.x += b1.x; a1.y += b1.y; a1.z += b1.z; a1.w += b1.w;
    const float* pr = pp + (size_t)r*8;
    float4 p0 = ((const float4*)pr)[0], p1 = ((const float4*)pr)[1];
    float w[8] = {p0.x,p0.y,p0.z,p0.w,p1.x,p1.y,p1.z,p1.w};
    #pragma unroll
    for (int p = 0; p < 8; p++){
      float4 w0 = ((const float4*)(Wpar + p*DD + colb))[0];
      float4 w1 = ((const float4*)(Wpar + p*DD + colb))[1];
      a0.x += w[p]*w0.x; a0.y += w[p]*w0.y; a0.z += w[p]*w0.z; a0.w += w[p]*w0.w;
      a1.x += w[p]*w1.x; a1.y += w[p]*w1.y; a1.z += w[p]*w1.z; a1.w += w[p]*w1.w;
    }
    u32x4 o;
    o.x = packbf(a0.x, a0.y); o.y = packbf(a0.z, a0.w);
    o.z = packbf(a1.x, a1.y); o.w = packbf(a1.z, a1.w);
    *(u32x4*)(hr + (size_t)r*DD + colb) = o;
  }
}

// ---------------- bucketed CSR build ----------------
__global__ __launch_bounds__(256) void bucket_hist(const int* __restrict__ er, const int* __restrict__ es,
                                                   int* __restrict__ gcnt){
  __shared__ int cnt[NBR + NBS];
  int t = threadIdx.x;
  for (int j = t; j < NBR + NBS; j += 256) cnt[j] = 0;
  __syncthreads();
  long i0 = (long)blockIdx.x * 2048;
  for (int j = t; j < 2048; j += 256){
    long i = i0 + j;
    if (i < EE){
      atomicAdd(&cnt[er[i] >> BSH], 1);
      atomicAdd(&cnt[NBR + (es[i] >> BSH)], 1);
    }
  }
  __syncthreads();
  for (int j = t; j < NBR + NBS; j += 256)
    if (cnt[j]) atomicAdd(&gcnt[j], cnt[j]);
}

__global__ __launch_bounds__(256) void bucket_scan(const int* __restrict__ gcnt,
        int* __restrict__ bktOffR, int* __restrict__ bktOffS,
        int* __restrict__ gCurR, int* __restrict__ gCurS){
  __shared__ int a[256];
  int t = threadIdx.x;
  int own = (t < NBR) ? gcnt[t] : 0;
  a[t] = own; __syncthreads();
  for (int d = 1; d < 256; d <<= 1){
    int x = (t >= d) ? a[t-d] : 0;
    __syncthreads(); a[t] += x; __syncthreads();
  }
  if (t < NBR){ int v = a[t] - own; bktOffR[t] = v; gCurR[t] = v; }
  if (t == 0) bktOffR[NBR] = EE;
  __syncthreads();
  own = (t < NBS) ? gcnt[NBR + t] : 0;
  a[t] = own; __syncthreads();
  for (int d = 1; d < 256; d <<= 1){
    int x = (t >= d) ? a[t-d] : 0;
    __syncthreads(); a[t] += x; __syncthreads();
  }
  if (t < NBS){ int v = a[t] - own; bktOffS[t] = v; gCurS[t] = v; }
  if (t == 0) bktOffS[NBS] = EE;
}

__global__ __launch_bounds__(256) void bin_edges(const int* __restrict__ er, const int* __restrict__ es,
        int* __restrict__ gCurR, int* __restrict__ gCurS,
        unsigned* __restrict__ recR, unsigned* __restrict__ recS){
  __shared__ unsigned stage[CHUNK];
  __shared__ unsigned char stageb[CHUNK];
  __shared__ int cnt[256], scn[256], pref[256], gbase[256], lcur[256];
  int t = threadIdx.x;
  int side = blockIdx.y;
  const int* dest = side ? es : er;
  const int* srca = side ? er : es;
  int* gCur = side ? gCurS : gCurR;
  unsigned* rec = side ? recS : recR;
  int nbkt = side ? NBS : NBR;
  long i0 = (long)blockIdx.x * CHUNK;
  int n = (EE - i0 < CHUNK) ? (int)(EE - i0) : CHUNK;
  cnt[t] = 0;
  __syncthreads();
  for (int j = t; j < n; j += 256)
    atomicAdd(&cnt[dest[i0 + j] >> BSH], 1);
  __syncthreads();
  scn[t] = cnt[t];
  __syncthreads();
  for (int d = 1; d < 256; d <<= 1){
    int x = (t >= d) ? scn[t-d] : 0;
    __syncthreads(); scn[t] += x; __syncthreads();
  }
  pref[t] = scn[t] - cnt[t];
  lcur[t] = scn[t] - cnt[t];
  if (t < nbkt && cnt[t] > 0) gbase[t] = atomicAdd(&gCur[t], cnt[t]);
  __syncthreads();
  for (int j = t; j < n; j += 256){
    int d = dest[i0 + j];
    int s = srca[i0 + j];
    int b = d >> BSH;
    int p = atomicAdd(&lcur[b], 1);
    stage[p] = ((unsigned)(d - (b << BSH)) << 18) | (unsigned)s;
    stageb[p] = (unsigned char)b;
  }
  __syncthreads();
  for (int e = t; e < n; e += 256){
    int b = stageb[e];
    rec[gbase[b] + (e - pref[b])] = stage[e];
  }
}

// Stage 4: scatter PRESCALED records: (dloc<<26) | (src*256)  [src byte offset]
__global__ __launch_bounds__(256) void build_csr(const unsigned* __restrict__ recR, const unsigned* __restrict__ recS,
        const int* __restrict__ bktOffR, const int* __restrict__ bktOffS,
        unsigned* __restrict__ csrR, unsigned* __restrict__ csrS,
        int* __restrict__ offsR, int* __restrict__ offsS){
  __shared__ int hist[1024], pref[1024], cur[1024], ws[256];
  int t = threadIdx.x;
  int bb = blockIdx.x;
  const unsigned* rec; const int* bktOff; unsigned* csr; int* offs; int N;
  if (bb < NBR){ rec = recR; bktOff = bktOffR; csr = csrR; offs = offsR; N = NR; }
  else { bb -= NBR; rec = recS; bktOff = bktOffS; csr = csrS; offs = offsS; N = NS; }
  int d0 = bb << BSH;
  int base = bktOff[bb], cnt_ = bktOff[bb+1] - base;
  #pragma unroll
  for (int j = 0; j < 4; j++) hist[t*4+j] = 0;
  __syncthreads();
  for (int e = t; e < cnt_; e += 256)
    atomicAdd(&hist[rec[base + e] >> 18], 1);
  __syncthreads();
  int s = 0, h[4];
  #pragma unroll
  for (int j = 0; j < 4; j++){ h[j] = hist[t*4+j]; s += h[j]; }
  ws[t] = s;
  __syncthreads();
  for (int d = 1; d < 256; d <<= 1){
    int x = (t >= d) ? ws[t-d] : 0;
    __syncthreads(); ws[t] += x; __syncthreads();
  }
  int run = ws[t] - s;
  #pragma unroll
  for (int j = 0; j < 4; j++){ pref[t*4+j] = run; cur[t*4+j] = base + run; run += h[j]; }
  __syncthreads();
  int DPB = N - d0; if (DPB > 1024) DPB = 1024;
  #pragma unroll
  for (int j = 0; j < 4; j++){
    int i = t*4 + j;
    if (i < DPB) offs[d0 + i] = base + pref[i];
  }
  if (t == 0 && d0 + DPB == N) offs[N] = EE;
  __syncthreads();
  for (int e = t; e < cnt_; e += 256){
    unsigned r = rec[base + e];
    int pos = atomicAdd(&cur[r >> 18], 1);
    csr[pos] = (((r >> 18) & 31u) << 26) | ((r & 0x3FFFFu) << 8);  // dloc<<26 | src byte-offset
  }
}

// ============ fused streaming-gather + concat-GEMM + bias + relu ============
// Block = one 32-row tile. Phase 1: each wave owns 8 rows; one edge per
// wave-instruction (64 lanes x 4B = full 256B row). Wave-uniform control is
// forced into the SCALAR pipe (readfirstlane): csr records + row base addresses
// live in SGPRs, the row load is saddr-form with a loop-invariant lane*4 offset.
// 8-deep prefetch ring doubles bytes in flight. Plain swizzled LDS store at
// row boundaries (rows wave-exclusive -> no atomics, no divergence).
// Phase 2: swapped-operand MFMA (W as A, H/msg as B) -> row-major 8B stores.
__global__ __launch_bounds__(256) void fused_layer(
        const unsigned short* __restrict__ gsrc,   // gather source rows (bf16)
        const unsigned short* __restrict__ hself,  // self features (bf16)
        const int* __restrict__ offs, const unsigned* __restrict__ csr,
        const unsigned short* __restrict__ Wp, const float* __restrict__ bias,
        unsigned short* __restrict__ hout)
{
  __shared__ unsigned short msgT[32*DD];   // 8 KB; 16B chunks swizzled: slot = c16 ^ (row&7)
  int t = threadIdx.x;
  int lane = t & 63;
  int w = t >> 6;
  int quad = lane >> 4, rlo = lane & 15;
  int row0 = blockIdx.x * 32;

  // zero-init msg tile (covers empty rows)
  for (int i = t; i < 2048; i += 256) ((unsigned*)msgT)[i] = 0u;
  __syncthreads();

  // ---- phase 1: wave streams the edges of its 8 rows (scalar control) ----
  {
    int rbeg = row0 + w*8;
    int k  = __builtin_amdgcn_readfirstlane(offs[rbeg]);
    int ke = __builtin_amdgcn_readfirstlane(offs[rbeg + 8]);
    int c16 = lane >> 2, sub4 = lane & 3;
    const char* gbase = (const char*)gsrc;
    float a0 = 0.f, a1 = 0.f;
    int cur = -1;
    unsigned rc[8]; unsigned pv[8];
    if (k < ke){
      #pragma unroll
      for (int i = 0; i < 8; i++){
        int kk = (k + i < ke) ? (k + i) : (ke - 1);
        rc[i] = (unsigned)__builtin_amdgcn_readfirstlane(csr[kk]);   // SGPR record
      }
      #pragma unroll
      for (int i = 0; i < 8; i++)
        pv[i] = *(const unsigned*)(gbase + (rc[i] & 0x03FFFF00u) + lane*4);  // saddr + v_off
      while (k < ke){
        unsigned rc2[8], pv2[8];
        int kn = k + 8;
        #pragma unroll
        for (int i = 0; i < 8; i++){
          int kk = (kn + i < ke) ? (kn + i) : (ke - 1);
          rc2[i] = (unsigned)__builtin_amdgcn_readfirstlane(csr[kk]);
        }
        #pragma unroll
        for (int i = 0; i < 8; i++)
          pv2[i] = *(const unsigned*)(gbase + (rc2[i] & 0x03FFFF00u) + lane*4);
        #pragma unroll
        for (int i = 0; i < 8; i++){
          if (k + i < ke){                            // scalar compare (k,ke,i uniform)
            int dl = (int)(rc[i] >> 26);              // scalar
            if (dl != cur){                           // scalar branch
              if (cur >= 0)
                *(unsigned*)(msgT + cur*DD + ((c16 ^ (cur & 7)) << 3) + (sub4 << 1)) = packbf(a0, a1);
              a0 = 0.f; a1 = 0.f;
              cur = dl;
            }
            a0 += bflo(pv[i]); a1 += bfhi(pv[i]);
          }
        }
        #pragma unroll
        for (int i = 0; i < 8; i++){ rc[i] = rc2[i]; pv[i] = pv2[i]; }
        k = kn;
      }
      if (cur >= 0)
        *(unsigned*)(msgT + cur*DD + ((c16 ^ (cur & 7)) << 3) + (sub4 << 1)) = packbf(a0, a1);
    }
  }
  __syncthreads();

  // ---- phase 2: MFMA. W = A-operand, H/msg = B-operand. Wave -> 32-col strip. ----
  int ct0 = w * 2;
  bf16x8 wf[16];                         // [ks][c]
  #pragma unroll
  for (int ks = 0; ks < 8; ks++){
    wf[ks*2+0] = *(const bf16x8*)(Wp + (size_t)(((ct0+0)*8 + ks)*64 + lane) * 8);
    wf[ks*2+1] = *(const bf16x8*)(Wp + (size_t)(((ct0+1)*8 + ks)*64 + lane) * 8);
  }
  bf16x8 Hb0[4], Hb1[4];
  #pragma unroll
  for (int ks = 0; ks < 4; ks++){
    int kloc = ks*32 + quad*8;
    Hb0[ks] = *(const bf16x8*)(hself + (size_t)(row0 + rlo) * DD + kloc);
    Hb1[ks] = *(const bf16x8*)(hself + (size_t)(row0 + 16 + rlo) * DD + kloc);
  }
  bf16x8 Mb0[4], Mb1[4];
  #pragma unroll
  for (int ks2 = 0; ks2 < 4; ks2++){
    int c8 = ks2*4 + quad;               // 16B chunk index 0..15
    int lr0 = rlo, lr1 = 16 + rlo;
    Mb0[ks2] = *(const bf16x8*)(msgT + lr0*DD + ((c8 ^ (lr0 & 7)) * 8));
    Mb1[ks2] = *(const bf16x8*)(msgT + lr1*DD + ((c8 ^ (lr1 & 7)) * 8));
  }

  f32x4 acc[2][2];
  #pragma unroll
  for (int i = 0; i < 2; i++)
    #pragma unroll
    for (int j = 0; j < 2; j++){ f32x4 z = {0.f,0.f,0.f,0.f}; acc[i][j] = z; }

  #pragma unroll
  for (int ks = 0; ks < 4; ks++){
    acc[0][0] = __builtin_amdgcn_mfma_f32_16x16x32_bf16(wf[ks*2+0], Hb0[ks], acc[0][0], 0, 0, 0);
    acc[0][1] = __builtin_amdgcn_mfma_f32_16x16x32_bf16(wf[ks*2+1], Hb0[ks], acc[0][1], 0, 0, 0);
    acc[1][0] = __builtin_amdgcn_mfma_f32_16x16x32_bf16(wf[ks*2+0], Hb1[ks], acc[1][0], 0, 0, 0);
    acc[1][1] = __builtin_amdgcn_mfma_f32_16x16x32_bf16(wf[ks*2+1], Hb1[ks], acc[1][1], 0, 0, 0);
  }
  #pragma unroll
  for (int ks2 = 0; ks2 < 4; ks2++){
    int ks = 4 + ks2;
    acc[0][0] = __builtin_amdgcn_mfma_f32_16x16x32_bf16(wf[ks*2+0], Mb0[ks2], acc[0][0], 0, 0, 0);
    acc[0][1] = __builtin_amdgcn_mfma_f32_16x16x32_bf16(wf[ks*2+1], Mb0[ks2], acc[0][1], 0, 0, 0);
    acc[1][0] = __builtin_amdgcn_mfma_f32_16x16x32_bf16(wf[ks*2+0], Mb1[ks2], acc[1][0], 0, 0, 0);
    acc[1][1] = __builtin_amdgcn_mfma_f32_16x16x32_bf16(wf[ks*2+1], Mb1[ks2], acc[1][1], 0, 0, 0);
  }

  // epilogue: acc[rb][c][i] = out[row0+rb*16+rlo][(ct0+c)*16 + quad*4 + i]
  #pragma unroll
  for (int c = 0; c < 2; c++){
    float4 bv = *(const float4*)(bias + (ct0+c)*16 + quad*4);
    #pragma unroll
    for (int rb = 0; rb < 2; rb++){
      int row = row0 + rb*16 + rlo;
      float v0 = acc[rb][c][0] + bv.x;
      float v1 = acc[rb][c][1] + bv.y;
      float v2 = acc[rb][c][2] + bv.z;
      float v3 = acc[rb][c][3] + bv.w;
      v0 = v0 > 0.f ? v0 : 0.f;
      v1 = v1 > 0.f ? v1 : 0.f;
      v2 = v2 > 0.f ? v2 : 0.f;
      v3 = v3 > 0.f ? v3 : 0.f;
      u32x2 o; o.x = packbf(v0, v1); o.y = packbf(v2, v3);
      *(u32x2*)(hout + (size_t)row*DD + (ct0+c)*16 + quad*4) = o;
    }
  }
}

// ---------------- segment-mean pooling: 16B loads, 2-stage reduce ----------------
__global__ __launch_bounds__(256) void pool(const unsigned short* __restrict__ hs,
        const unsigned short* __restrict__ hr, float* __restrict__ out){
  __shared__ float red[16][128];
  int b = blockIdx.x, part = blockIdx.y;   // part<4: species, else reactions (500 rows each)
  int t = threadIdx.x;
  int rg = t >> 4, sub = t & 15;
  const unsigned short* src; int row0, outoff; float scale;
  if (part < 4){ src = hs; row0 = b*NSP + part*500; outoff = b*256; scale = 1.f/NSP; }
  else { src = hr; row0 = b*NRP + (part-4)*500; outoff = b*256 + 128; scale = 1.f/NRP; }
  float a0=0,a1=0,a2=0,a3=0,a4=0,a5=0,a6=0,a7=0;
  for (int r = rg; r < 500; r += 16){
    u32x4 p = *(const u32x4*)(src + (size_t)(row0+r)*DD + sub*8);
    a0 += bflo(p.x); a1 += bfhi(p.x);
    a2 += bflo(p.y); a3 += bfhi(p.y);
    a4 += bflo(p.z); a5 += bfhi(p.z);
    a6 += bflo(p.w); a7 += bfhi(p.w);
  }
  float* rr = &red[rg][sub*8];
  rr[0]=a0; rr[1]=a1; rr[2]=a2; rr[3]=a3; rr[4]=a4; rr[5]=a5; rr[6]=a6; rr[7]=a7;
  __syncthreads();
  if (t < 128){
    float s = 0.f;
    #pragma unroll
    for (int g = 0; g < 16; g++) s += red[g][t];
    atomicAdd(&out[outoff + t], s * scale);
  }
}

extern "C" void kernel_launch(void* const* d_in, const int* in_sizes, int n_in,
                              void* d_out, int out_size, void* d_ws, size_t ws_size,
                              hipStream_t stream)
{
  const int*   si   = (const int*)d_in[0];
  const int*   ext  = (const int*)d_in[1];
  const int*   tid  = (const int*)d_in[2];
  const float* pp   = (const float*)d_in[3];
  const int*   es   = (const int*)d_in[4];
  const int*   er   = (const int*)d_in[5];
  const float* st   = (const float*)d_in[8];
  const float* et   = (const float*)d_in[9];
  const float* tt   = (const float*)d_in[10];
  const float* Wpar = (const float*)d_in[11];
  const float* bpar = (const float*)d_in[12];
  const float* Wr   = (const float*)d_in[13];
  const float* br   = (const float*)d_in[14];
  const float* Ws   = (const float*)d_in[15];
  const float* bs   = (const float*)d_in[16];
  float* out = (float*)d_out;

  char* basep = (char*)d_ws; size_t off = 0;
  auto alloc = [&](size_t bytes)->char*{
    char* r = basep + off; off = (off + bytes + 255) & ~(size_t)255; return r;
  };
  unsigned short* hs0 = (unsigned short*)alloc((size_t)NS*DD*2);
  unsigned short* hs1 = (unsigned short*)alloc((size_t)NS*DD*2);
  unsigned short* hr0 = (unsigned short*)alloc((size_t)NR*DD*2);
  unsigned short* hr1 = (unsigned short*)alloc((size_t)NR*DD*2);
  unsigned short* Wp  = (unsigned short*)alloc((size_t)4*32768*2);
  int* offsR = (int*)alloc((size_t)(NR+1)*4);
  int* offsS = (int*)alloc((size_t)(NS+1)*4);
  unsigned* csrR = (unsigned*)alloc((size_t)EE*4);
  unsigned* csrS = (unsigned*)alloc((size_t)EE*4);
  int* gcnt   = (int*)alloc(2048);
  int* bktOffR= (int*)alloc(2048);
  int* bktOffS= (int*)alloc(2048);
  int* gCurR  = (int*)alloc(2048);
  int* gCurS  = (int*)alloc(2048);
  // rec arrays only live during CSR build; alias into the ping buffers
  // (hs1 / hr1 are first written at layer-0 fused dispatches, after build_csr).
  unsigned* recR = (unsigned*)hs1;            // 4 MB within 25.6 MB
  unsigned* recS = (unsigned*)hr1;            // 4 MB within 51.2 MB

  hipMemsetAsync(gcnt, 0, 2048, stream);
  hipMemsetAsync(d_out, 0, (size_t)out_size*4, stream);

  pack_w<<<512, 256, 0, stream>>>(Wr, Ws, Wp);
  init_all<<<(NS+NR)*16/256, 256, 0, stream>>>(si, ext, tid, pp, st, et, tt, Wpar, bpar, hs0, hr0);

  bucket_hist<<<(EE + 2047)/2048, 256, 0, stream>>>(er, es, gcnt);
  bucket_scan<<<1, 256, 0, stream>>>(gcnt, bktOffR, bktOffS, gCurR, gCurS);
  bin_edges<<<dim3((EE + CHUNK - 1)/CHUNK, 2), 256, 0, stream>>>(er, es, gCurR, gCurS, recR, recS);
  build_csr<<<NBR + NBS, 256, 0, stream>>>(recR, recS, bktOffR, bktOffS, csrR, csrS, offsR, offsS);

  // layer 0
  fused_layer<<<NR/32, 256, 0, stream>>>(hs0, hr0, offsR, csrR, Wp + (size_t)0*32768, br + (size_t)0*DD, hr1);
  fused_layer<<<NS/32, 256, 0, stream>>>(hr1, hs0, offsS, csrS, Wp + (size_t)2*32768, bs + (size_t)0*DD, hs1);
  // layer 1
  fused_layer<<<NR/32, 256, 0, stream>>>(hs1, hr1, offsR, csrR, Wp + (size_t)1*32768, br + (size_t)1*DD, hr0);
  fused_layer<<<NS/32, 256, 0, stream>>>(hr0, hs1, offsS, csrS, Wp + (size_t)3*32768, bs + (size_t)1*DD, hs0);

  pool<<<dim3(NB, 12), 256, 0, stream>>>(hs0, hr0, out);
}